// Round 5
// baseline (1606.908 us; speedup 1.0000x reference)
//
#include <hip/hip_runtime.h>
#include <math.h>

#define CDIM 256
#define HDIM 512
#define KCLS 20
#define MAXSEG 8
#define TILE_R 32
#define NTHR 512
#define GRIDA 512

// async global->LDS, 16B per lane (dest = uniform base + lane*16)
__device__ __forceinline__ void gload_lds16(const void* g, void* l) {
  __builtin_amdgcn_global_load_lds(
      (__attribute__((address_space(1))) const void*)g,
      (__attribute__((address_space(3))) void*)l, 16, 0, 0);
}

// ---------------------------------------------------------------------------
// Pass A: single read of feat. Double-buffered 2x32KB LDS, global_load_lds
// staging with pre-swizzled global source, ONE barrier per round:
//   round: [stage tile t+1 -> buf^1 (async DMA)] [compute buf from LDS]
//          [__syncthreads: drains the DMA (issued a full compute phase ago)]
// Swizzle: logical float4 (rr,c4) stored at physical rr*64 + (c4 ^ rr)
//   (full 5-bit row XOR). Head read (fixed c4, 32 rows x2 broadcast): 2-way,
//   free. Colsum read (fixed rr, lanes=c4): permutation, free. Staging write:
//   linear (lane=phys slot), source column = lane ^ rr per-lane.
// ---------------------------------------------------------------------------
__global__ __launch_bounds__(NTHR, 4) void fused_pool_head_kernel(
    const float* __restrict__ feat, const int* __restrict__ offset,
    const float* __restrict__ W_head, const float* __restrict__ b_head,
    float* __restrict__ sums, float* __restrict__ out, int n, int nseg) {
  __shared__ float tile[2][TILE_R * CDIM];  // 2 x 32 KB
  int t = threadIdx.x;
  int lane = t & 63;
  int wv = t >> 6;

  int ntiles = (n + TILE_R - 1) / TILE_R;
  int nb = (int)gridDim.x;
  int t0 = (int)blockIdx.x;
  if (t0 >= ntiles) return;

  int off[MAXSEG];
#pragma unroll
  for (int q = 0; q < MAXSEG; ++q) off[q] = (q < nseg) ? offset[q] : 0x7fffffff;

  // ---- head mapping: 16 half-wave slots over 20 classes ----
  int row = lane & 31;
  int half = lane >> 5;
  int slot = wv * 2 + half;
  int kb = (slot < 4) ? (2 * slot) : (4 + slot);  // waves0-1: 2cls, else 1cls
  int ncls = (wv < 2) ? 2 : 1;                    // wave-uniform
  const float4* wk0 = (const float4*)(W_head + (size_t)kb * CDIM);
  const float4* wk1 = (const float4*)(W_head + (size_t)(kb + 1) * CDIM);
  float bh0 = b_head[kb];
  float bh1 = (ncls == 2) ? b_head[kb + 1] : 0.f;

  // ---- colsum mapping: c4-column group, 4-row group ----
  int c4s = t & 63;  // float4 column 0..63
  int rg = t >> 6;   // rows rg*4 .. rg*4+3
  float4 colacc = make_float4(0.f, 0.f, 0.f, 0.f);
  int cur_seg = -1;

  const float4* src = (const float4*)feat;

  auto flush = [&]() {
    if (cur_seg >= 0) {
      float* dst = &sums[cur_seg * CDIM + c4s * 4];
      atomicAdd(dst + 0, colacc.x);
      atomicAdd(dst + 1, colacc.y);
      atomicAdd(dst + 2, colacc.z);
      atomicAdd(dst + 3, colacc.w);
      colacc = make_float4(0.f, 0.f, 0.f, 0.f);
    }
  };

  auto stage = [&](int bufidx, int tl) {
    long r0 = (long)tl * TILE_R;
#pragma unroll
    for (int i = 0; i < 4; ++i) {
      int rr = wv * 4 + i;                  // wave-uniform dest row
      long r = r0 + rr;
      if (r >= n) r = n - 1;                // clamp: valid addr, data unused
      const float4* gsrc = src + r * 64 + (lane ^ rr);  // pre-swizzled source
      gload_lds16((const void*)gsrc, (void*)&tile[bufidx][rr * CDIM]);
    }
  };

  auto compute = [&](int bufidx, int tl) {
    long r0 = (long)tl * TILE_R;
    int rows = (int)(((long)n - r0) < TILE_R ? ((long)n - r0) : TILE_R);
    const float4* t4 = (const float4*)&tile[bufidx][0];

    // ---- (1) per-segment column sums ----
    {
      int rlo = rg * 4, rhi = rlo + 4;
      if (rhi > rows) rhi = rows;
      if (rlo < rhi) {
        long ra = r0 + rlo, rb = r0 + rhi - 1;
        int s0 = 0, s1 = 0;
#pragma unroll
        for (int q = 0; q < MAXSEG - 1; ++q) {
          s0 += (ra >= off[q]) ? 1 : 0;
          s1 += (rb >= off[q]) ? 1 : 0;
        }
        if (s0 == s1) {  // fast path: slice in one segment
          if (s0 != cur_seg) { flush(); cur_seg = s0; }
          float4 a = make_float4(0.f, 0.f, 0.f, 0.f);
#pragma unroll
          for (int rr = rlo; rr < rhi; ++rr) {
            float4 v = t4[rr * 64 + (c4s ^ rr)];
            a.x += v.x; a.y += v.y; a.z += v.z; a.w += v.w;
          }
          colacc.x += a.x; colacc.y += a.y; colacc.z += a.z; colacc.w += a.w;
        } else {
          for (int rr = rlo; rr < rhi; ++rr) {
            long r = r0 + rr;
            int s = 0;
#pragma unroll
            for (int q = 0; q < MAXSEG - 1; ++q) s += (r >= off[q]) ? 1 : 0;
            if (s != cur_seg) { flush(); cur_seg = s; }
            float4 v = t4[rr * 64 + (c4s ^ rr)];
            colacc.x += v.x; colacc.y += v.y; colacc.z += v.z; colacc.w += v.w;
          }
        }
      }
    }

    // ---- (2) head partial: out[r][kb..] = feat[r]·W_head + b_head ----
    if (row < rows) {
      const float4* trow = t4 + row * 64;
      if (ncls == 2) {
        float a0 = bh0, a1 = bh1;
#pragma unroll 4
        for (int c4 = 0; c4 < 64; ++c4) {
          float4 f = trow[c4 ^ row];
          float4 w0 = wk0[c4], w1 = wk1[c4];
          a0 = fmaf(f.x, w0.x, a0); a1 = fmaf(f.x, w1.x, a1);
          a0 = fmaf(f.y, w0.y, a0); a1 = fmaf(f.y, w1.y, a1);
          a0 = fmaf(f.z, w0.z, a0); a1 = fmaf(f.z, w1.z, a1);
          a0 = fmaf(f.w, w0.w, a0); a1 = fmaf(f.w, w1.w, a1);
        }
        float2 st = make_float2(a0, a1);  // kb even -> 8B aligned
        *(float2*)(out + (r0 + row) * KCLS + kb) = st;
      } else {
        float a0 = bh0;
#pragma unroll 4
        for (int c4 = 0; c4 < 64; ++c4) {
          float4 f = trow[c4 ^ row];
          float4 w0 = wk0[c4];
          a0 = fmaf(f.x, w0.x, a0);
          a0 = fmaf(f.y, w0.y, a0);
          a0 = fmaf(f.z, w0.z, a0);
          a0 = fmaf(f.w, w0.w, a0);
        }
        out[(r0 + row) * KCLS + kb] = a0;
      }
    }
  };

  // ---- prologue ----
  stage(0, t0);
  __syncthreads();  // drain first tile's DMA

  int cur = 0;
  for (int tl = t0; tl < ntiles; tl += nb) {
    int nxt = tl + nb;
    if (nxt < ntiles) stage(cur ^ 1, nxt);  // async DMA into other buffer
    compute(cur, tl);                        // LDS-only reads
    __syncthreads();                         // joins + drains next-tile DMA
    cur ^= 1;
  }
  flush();
}

// ---------------------------------------------------------------------------
// L1: h[s][j], wave-task = gate column j. lane = (seg, c-chunk); coalesced
// W_ih float4 rows; 3-step shfl_xor reduce within 8-lane seg groups.
// ---------------------------------------------------------------------------
__global__ __launch_bounds__(256) void lstm_h_kernel(
    const float* __restrict__ sums, const int* __restrict__ offset,
    const float* __restrict__ W_ih, const float* __restrict__ b_ih,
    const float* __restrict__ b_hh, float* __restrict__ h, int nseg) {
  __shared__ float pooled[MAXSEG * CDIM];
  int t = threadIdx.x;
  {
    int prev = 0;
    for (int s = 0; s < MAXSEG; ++s) {
      int cur = (s < nseg) ? offset[s] : prev;
      float cnt = (float)(cur - prev);
      float inv = (cnt > 0.f) ? 1.f / cnt : 0.f;
      pooled[s * CDIM + t] = sums[s * CDIM + t] * inv;
      prev = cur;
    }
  }
  __syncthreads();

  int wv = t >> 6, l = t & 63;
  int j = (int)blockIdx.x * 4 + wv;
  int s = l >> 3, ch = l & 7;

  const float4* Wi4 = (const float4*)(W_ih + (size_t)(0 * HDIM + j) * CDIM);
  const float4* Wg4 = (const float4*)(W_ih + (size_t)(2 * HDIM + j) * CDIM);
  const float4* Wo4 = (const float4*)(W_ih + (size_t)(3 * HDIM + j) * CDIM);
  const float4* p4 = (const float4*)(pooled + s * CDIM);

  float di = 0.f, dg = 0.f, dd = 0.f;
#pragma unroll
  for (int i = 0; i < 8; ++i) {
    int c4 = ch * 8 + i;
    float4 p = p4[c4];
    float4 wi = Wi4[c4], wg = Wg4[c4], wo = Wo4[c4];
    di = fmaf(p.x, wi.x, di); di = fmaf(p.y, wi.y, di);
    di = fmaf(p.z, wi.z, di); di = fmaf(p.w, wi.w, di);
    dg = fmaf(p.x, wg.x, dg); dg = fmaf(p.y, wg.y, dg);
    dg = fmaf(p.z, wg.z, dg); dg = fmaf(p.w, wg.w, dg);
    dd = fmaf(p.x, wo.x, dd); dd = fmaf(p.y, wo.y, dd);
    dd = fmaf(p.z, wo.z, dd); dd = fmaf(p.w, wo.w, dd);
  }
#pragma unroll
  for (int m = 1; m < 8; m <<= 1) {
    di += __shfl_xor(di, m);
    dg += __shfl_xor(dg, m);
    dd += __shfl_xor(dd, m);
  }
  if (ch == 0 && s < nseg) {
    di += b_ih[j] + b_hh[j];
    dg += b_ih[2 * HDIM + j] + b_hh[2 * HDIM + j];
    dd += b_ih[3 * HDIM + j] + b_hh[3 * HDIM + j];
    float ig = 1.f / (1.f + expf(-di));
    float gg = tanhf(dg);
    float og = 1.f / (1.f + expf(-dd));
    h[(size_t)s * HDIM + j] = og * tanhf(ig * gg);
  }
}

// ---------------------------------------------------------------------------
// L2: ctx[s][col] = b_proj[col] + h[s]·W_proj[col].
// ---------------------------------------------------------------------------
__global__ __launch_bounds__(256) void ctx_kernel(
    const float* __restrict__ h, const float* __restrict__ W_proj,
    const float* __restrict__ b_proj, float* __restrict__ ctx, int nseg) {
  __shared__ float hs[MAXSEG * HDIM];
  int t = threadIdx.x;
  {
    const float4* hsrc = (const float4*)h;
    float4* hdst = (float4*)hs;
#pragma unroll
    for (int i = 0; i < 4; ++i) hdst[i * 256 + t] = hsrc[i * 256 + t];
  }
  __syncthreads();

  int wv = t >> 6, l = t & 63;
  int col = (int)blockIdx.x * 4 + wv;
  int s = l >> 3, ch = l & 7;

  const float4* Wp4 = (const float4*)(W_proj + (size_t)col * HDIM);
  const float4* h4 = (const float4*)(hs + s * HDIM);
  float acc = 0.f;
#pragma unroll
  for (int i = 0; i < 16; ++i) {
    int j4 = ch * 16 + i;
    float4 hv = h4[j4];
    float4 w = Wp4[j4];
    acc = fmaf(hv.x, w.x, acc); acc = fmaf(hv.y, w.y, acc);
    acc = fmaf(hv.z, w.z, acc); acc = fmaf(hv.w, w.w, acc);
  }
#pragma unroll
  for (int m = 1; m < 8; m <<= 1) acc += __shfl_xor(acc, m);
  if (ch == 0 && s < nseg) ctx[s * CDIM + col] = acc + b_proj[col];
}

// ---------------------------------------------------------------------------
// L3: delta[s][k] = ctx[s]·W_head[k]  (b_head already applied in pass A).
// ---------------------------------------------------------------------------
__global__ __launch_bounds__(256) void delta_kernel(
    const float* __restrict__ ctx, const float* __restrict__ W_head,
    float* __restrict__ delta, int nseg) {
  __shared__ float cs[MAXSEG * CDIM];
  int t = threadIdx.x;
  {
    const float4* csrc = (const float4*)ctx;
    float4* cdst = (float4*)cs;
#pragma unroll
    for (int i = 0; i < 2; ++i) cdst[i * 256 + t] = csrc[i * 256 + t];
  }
  __syncthreads();

  int wv = t >> 6, l = t & 63;
  int k = (int)blockIdx.x * 4 + wv;
  if (k >= KCLS) return;
  int s = l >> 3, ch = l & 7;

  const float4* Wh4 = (const float4*)(W_head + (size_t)k * CDIM);
  const float4* c4 = (const float4*)(cs + s * CDIM);
  float acc = 0.f;
#pragma unroll
  for (int i = 0; i < 8; ++i) {
    int idx = ch * 8 + i;
    float4 cv = c4[idx];
    float4 w = Wh4[idx];
    acc = fmaf(cv.x, w.x, acc); acc = fmaf(cv.y, w.y, acc);
    acc = fmaf(cv.z, w.z, acc); acc = fmaf(cv.w, w.w, acc);
  }
#pragma unroll
  for (int m = 1; m < 8; m <<= 1) acc += __shfl_xor(acc, m);
  if (ch == 0 && s < nseg) delta[s * KCLS + k] = acc;
}

// ---------------------------------------------------------------------------
// Pass C: out[r][k] += delta[seg(r)][k], float4 grid-stride.
// ---------------------------------------------------------------------------
__global__ __launch_bounds__(256) void add_delta_kernel(
    float* __restrict__ out, const int* __restrict__ offset,
    const float* __restrict__ delta, int n, int nseg) {
  __shared__ float dl[MAXSEG * KCLS];
  int t = threadIdx.x;
  if (t < MAXSEG * KCLS) dl[t] = (t < nseg * KCLS) ? delta[t] : 0.f;
  __syncthreads();

  int off[MAXSEG];
#pragma unroll
  for (int q = 0; q < MAXSEG; ++q) off[q] = (q < nseg) ? offset[q] : 0x7fffffff;

  long tot = (long)n * (KCLS / 4);
  long stride = (long)gridDim.x * 256;
  for (long e4 = (long)blockIdx.x * 256 + t; e4 < tot; e4 += stride) {
    long row = e4 / 5;
    int k0 = (int)(e4 - row * 5) * 4;
    int s = 0;
#pragma unroll
    for (int q = 0; q < MAXSEG - 1; ++q) s += (row >= off[q]) ? 1 : 0;
    float4 v = ((float4*)out)[e4];
    const float* d = &dl[s * KCLS + k0];
    v.x += d[0]; v.y += d[1]; v.z += d[2]; v.w += d[3];
    ((float4*)out)[e4] = v;
  }
}

extern "C" void kernel_launch(void* const* d_in, const int* in_sizes, int n_in,
                              void* d_out, int out_size, void* d_ws, size_t ws_size,
                              hipStream_t stream) {
  const float* feat   = (const float*)d_in[0];
  const int*   offset = (const int*)d_in[1];
  const float* W_ih   = (const float*)d_in[2];
  const float* b_ih   = (const float*)d_in[3];
  // d_in[4] = W_hh : unused (h0 == 0)
  const float* b_hh   = (const float*)d_in[5];
  const float* W_proj = (const float*)d_in[6];
  const float* b_proj = (const float*)d_in[7];
  const float* W_head = (const float*)d_in[8];
  const float* b_head = (const float*)d_in[9];
  float* out = (float*)d_out;

  int n = in_sizes[0] / CDIM;
  int nseg = in_sizes[1];
  if (nseg > MAXSEG) nseg = MAXSEG;

  float* ws    = (float*)d_ws;
  float* sums  = ws;                                    // 8*256
  float* h     = ws + MAXSEG * CDIM;                    // 8*512
  float* ctx   = ws + MAXSEG * CDIM + MAXSEG * HDIM;    // 8*256
  float* delta = ctx + MAXSEG * CDIM;                   // 8*20

  hipMemsetAsync(sums, 0, MAXSEG * CDIM * sizeof(float), stream);
  fused_pool_head_kernel<<<GRIDA, NTHR, 0, stream>>>(feat, offset, W_head, b_head,
                                                     sums, out, n, nseg);
  lstm_h_kernel<<<128, 256, 0, stream>>>(sums, offset, W_ih, b_ih, b_hh, h, nseg);
  ctx_kernel<<<64, 256, 0, stream>>>(h, W_proj, b_proj, ctx, nseg);
  delta_kernel<<<5, 256, 0, stream>>>(ctx, W_head, delta, nseg);
  add_delta_kernel<<<2048, 256, 0, stream>>>(out, offset, delta, n, nseg);
}

// Round 6
// 681.109 us; speedup vs baseline: 2.3593x; 2.3593x over previous
//
#include <hip/hip_runtime.h>
#include <math.h>

#define CDIM 256
#define HDIM 512
#define KCLS 20
#define MAXSEG 8
#define TILE_R 64
#define NTHR 512
#define GRIDA 256
#define F4_TILE (TILE_R * CDIM / 4)   // 4096 float4 per tile
#define F4_THR (F4_TILE / NTHR)       // 8 float4 per thread

// ---------------------------------------------------------------------------
// Pass A: single read of feat. 2x64KB LDS double buffer (1 block/CU),
// register staging, ONE raw s_barrier per round with lgkmcnt(0) ONLY —
// the next-next tile's global loads stay in flight ACROSS the barrier
// (T4 counted-vmcnt effect), so HBM never drains:
//   round r: [compute tile t from buf]
//            [ds_write t+1 -> buf^1  (auto vmcnt wait: issued 1 round ago)]
//            [issue loads t+2 -> regs]
//            [s_waitcnt lgkmcnt(0); s_barrier]
// Swizzle: logical float4 (rr,c4) at physical rr*64 + (c4 ^ rr) (full 6-bit
// row XOR): staging write / colsum read / head read all at structural floor.
// Work split: waves 0-3 = 3 head classes; waves 4-7 = 2 head classes + the
// per-segment column sums (balances barrier arrival).
// W_head: wave-uniform kb -> scalar (constant-cache) loads in the hot loop.
// ---------------------------------------------------------------------------
__global__ __launch_bounds__(NTHR) void fused_pool_head_kernel(
    const float* __restrict__ feat, const int* __restrict__ offset,
    const float* __restrict__ W_head, const float* __restrict__ b_head,
    float* __restrict__ sums, float* __restrict__ out, int n, int nseg) {
  __shared__ float4 tile4[2][F4_TILE];  // 2 x 64 KB
  int t = threadIdx.x;
  int lane = t & 63;
  int wv = t >> 6;

  int ntiles = (n + TILE_R - 1) / TILE_R;
  int nb = (int)gridDim.x;
  int t0 = (int)blockIdx.x;
  if (t0 >= ntiles) return;

  int off[MAXSEG];
#pragma unroll
  for (int q = 0; q < MAXSEG; ++q) off[q] = (q < nseg) ? offset[q] : 0x7fffffff;

  // ---- head class mapping (wave-uniform -> scalar W loads) ----
  int kb_ = (wv < 4) ? wv * 3 : 12 + (wv - 4) * 2;
  int kb = __builtin_amdgcn_readfirstlane(kb_);
  float bh0 = b_head[kb], bh1 = b_head[kb + 1];
  float bh2 = (wv < 4) ? b_head[kb + 2] : 0.f;

  // ---- colsum mapping (waves 4-7 only): c4 column = lane, rows rg*16.. ----
  int c4s = lane;
  int rg = wv - 4;  // 0..3 for colsum waves
  float4 colacc = make_float4(0.f, 0.f, 0.f, 0.f);
  int cur_seg = -1;

  const float4* src = (const float4*)feat;
  long lim = (long)n * (CDIM / 4);
  float4 stg[F4_THR];

  auto flush = [&]() {
    if (cur_seg >= 0) {
      float* dst = &sums[cur_seg * CDIM + c4s * 4];
      atomicAdd(dst + 0, colacc.x);
      atomicAdd(dst + 1, colacc.y);
      atomicAdd(dst + 2, colacc.z);
      atomicAdd(dst + 3, colacc.w);
      colacc = make_float4(0.f, 0.f, 0.f, 0.f);
    }
  };

  auto issue = [&](int tl) {
    long base = (long)tl * F4_TILE;
    if (base + F4_TILE <= lim) {
#pragma unroll
      for (int i = 0; i < F4_THR; ++i) stg[i] = src[base + i * NTHR + t];
    } else {
#pragma unroll
      for (int i = 0; i < F4_THR; ++i) {
        long idx = base + i * NTHR + t;
        stg[i] = (idx < lim) ? src[idx] : make_float4(0.f, 0.f, 0.f, 0.f);
      }
    }
  };
  auto dswrite = [&](int b) {
#pragma unroll
    for (int i = 0; i < F4_THR; ++i) {
      int idx = i * NTHR + t;
      int rr = idx >> 6, c4 = idx & 63;
      tile4[b][rr * 64 + (c4 ^ rr)] = stg[i];
    }
  };

  auto compute = [&](int b, int tl) {
    long r0 = (long)tl * TILE_R;
    int rows = (int)(((long)n - r0) < TILE_R ? ((long)n - r0) : TILE_R);
    const float4* t4 = &tile4[b][0];

    // ---- (1) per-segment column sums: waves 4-7, 16 rows each ----
    if (wv >= 4) {
      int rlo = rg * 16, rhi = rlo + 16;
      if (rhi > rows) rhi = rows;
      if (rlo < rhi) {
        long ra = r0 + rlo, rb = r0 + rhi - 1;
        int s0 = 0, s1 = 0;
#pragma unroll
        for (int q = 0; q < MAXSEG - 1; ++q) {
          s0 += (ra >= off[q]) ? 1 : 0;
          s1 += (rb >= off[q]) ? 1 : 0;
        }
        if (s0 == s1) {  // fast path: whole slice in one segment
          if (s0 != cur_seg) { flush(); cur_seg = s0; }
          float4 a = make_float4(0.f, 0.f, 0.f, 0.f);
#pragma unroll
          for (int rr = rlo; rr < rhi; ++rr) {
            float4 v = t4[rr * 64 + (c4s ^ rr)];
            a.x += v.x; a.y += v.y; a.z += v.z; a.w += v.w;
          }
          colacc.x += a.x; colacc.y += a.y; colacc.z += a.z; colacc.w += a.w;
        } else {
          for (int rr = rlo; rr < rhi; ++rr) {
            long r = r0 + rr;
            int s = 0;
#pragma unroll
            for (int q = 0; q < MAXSEG - 1; ++q) s += (r >= off[q]) ? 1 : 0;
            if (s != cur_seg) { flush(); cur_seg = s; }
            float4 v = t4[rr * 64 + (c4s ^ rr)];
            colacc.x += v.x; colacc.y += v.y; colacc.z += v.z; colacc.w += v.w;
          }
        }
      }
    }

    // ---- (2) head partial: out[r][kb..] = feat[r]·W_head + b_head ----
    if (lane < rows) {
      const float4* trow = t4 + lane * 64;
      if (wv < 4) {
        float a0 = bh0, a1 = bh1, a2 = bh2;
        const float* w0 = W_head + (size_t)(kb + 0) * CDIM;
        const float* w1 = W_head + (size_t)(kb + 1) * CDIM;
        const float* w2 = W_head + (size_t)(kb + 2) * CDIM;
#pragma unroll 4
        for (int c4 = 0; c4 < 64; ++c4) {
          float4 f = trow[c4 ^ lane];
          int cb = c4 * 4;
          a0 = fmaf(f.x, w0[cb], a0);   a1 = fmaf(f.x, w1[cb], a1);   a2 = fmaf(f.x, w2[cb], a2);
          a0 = fmaf(f.y, w0[cb+1], a0); a1 = fmaf(f.y, w1[cb+1], a1); a2 = fmaf(f.y, w2[cb+1], a2);
          a0 = fmaf(f.z, w0[cb+2], a0); a1 = fmaf(f.z, w1[cb+2], a1); a2 = fmaf(f.z, w2[cb+2], a2);
          a0 = fmaf(f.w, w0[cb+3], a0); a1 = fmaf(f.w, w1[cb+3], a1); a2 = fmaf(f.w, w2[cb+3], a2);
        }
        float* orow = out + (r0 + lane) * KCLS + kb;
        orow[0] = a0; orow[1] = a1; orow[2] = a2;
      } else {
        float a0 = bh0, a1 = bh1;
        const float* w0 = W_head + (size_t)(kb + 0) * CDIM;
        const float* w1 = W_head + (size_t)(kb + 1) * CDIM;
#pragma unroll 4
        for (int c4 = 0; c4 < 64; ++c4) {
          float4 f = trow[c4 ^ lane];
          int cb = c4 * 4;
          a0 = fmaf(f.x, w0[cb], a0);   a1 = fmaf(f.x, w1[cb], a1);
          a0 = fmaf(f.y, w0[cb+1], a0); a1 = fmaf(f.y, w1[cb+1], a1);
          a0 = fmaf(f.z, w0[cb+2], a0); a1 = fmaf(f.z, w1[cb+2], a1);
          a0 = fmaf(f.w, w0[cb+3], a0); a1 = fmaf(f.w, w1[cb+3], a1);
        }
        float* orow = out + (r0 + lane) * KCLS + kb;
        orow[0] = a0; orow[1] = a1;
      }
    }
  };

  // ---- prologue: tile t0 -> buf0; issue t0+nb; barrier ----
  issue(t0);
  dswrite(0);                       // auto vmcnt wait on t0's loads
  if (t0 + nb < ntiles) issue(t0 + nb);
  asm volatile("s_waitcnt lgkmcnt(0)" ::: "memory");
  __builtin_amdgcn_s_barrier();
  __builtin_amdgcn_sched_barrier(0);

  int cur = 0;
  for (int tl = t0; tl < ntiles; tl += nb) {
    compute(cur, tl);
    int t1 = tl + nb;
    if (t1 < ntiles) {
      dswrite(cur ^ 1);             // stg holds t1's data (auto vmcnt wait)
      int t2 = t1 + nb;
      if (t2 < ntiles) issue(t2);   // in flight ACROSS the barrier
    }
    asm volatile("s_waitcnt lgkmcnt(0)" ::: "memory");
    __builtin_amdgcn_s_barrier();
    __builtin_amdgcn_sched_barrier(0);
    cur ^= 1;
  }
  flush();
}

// ---------------------------------------------------------------------------
// L1: h[s][j], wave-task = gate column j. lane = (seg, c-chunk); coalesced
// W_ih float4 rows; 3-step shfl_xor reduce within 8-lane seg groups.
// ---------------------------------------------------------------------------
__global__ __launch_bounds__(256) void lstm_h_kernel(
    const float* __restrict__ sums, const int* __restrict__ offset,
    const float* __restrict__ W_ih, const float* __restrict__ b_ih,
    const float* __restrict__ b_hh, float* __restrict__ h, int nseg) {
  __shared__ float pooled[MAXSEG * CDIM];
  int t = threadIdx.x;
  {
    int prev = 0;
    for (int s = 0; s < MAXSEG; ++s) {
      int cur = (s < nseg) ? offset[s] : prev;
      float cnt = (float)(cur - prev);
      float inv = (cnt > 0.f) ? 1.f / cnt : 0.f;
      pooled[s * CDIM + t] = sums[s * CDIM + t] * inv;
      prev = cur;
    }
  }
  __syncthreads();

  int wv = t >> 6, l = t & 63;
  int j = (int)blockIdx.x * 4 + wv;
  int s = l >> 3, ch = l & 7;

  const float4* Wi4 = (const float4*)(W_ih + (size_t)(0 * HDIM + j) * CDIM);
  const float4* Wg4 = (const float4*)(W_ih + (size_t)(2 * HDIM + j) * CDIM);
  const float4* Wo4 = (const float4*)(W_ih + (size_t)(3 * HDIM + j) * CDIM);
  const float4* p4 = (const float4*)(pooled + s * CDIM);

  float di = 0.f, dg = 0.f, dd = 0.f;
#pragma unroll
  for (int i = 0; i < 8; ++i) {
    int c4 = ch * 8 + i;
    float4 p = p4[c4];
    float4 wi = Wi4[c4], wg = Wg4[c4], wo = Wo4[c4];
    di = fmaf(p.x, wi.x, di); di = fmaf(p.y, wi.y, di);
    di = fmaf(p.z, wi.z, di); di = fmaf(p.w, wi.w, di);
    dg = fmaf(p.x, wg.x, dg); dg = fmaf(p.y, wg.y, dg);
    dg = fmaf(p.z, wg.z, dg); dg = fmaf(p.w, wg.w, dg);
    dd = fmaf(p.x, wo.x, dd); dd = fmaf(p.y, wo.y, dd);
    dd = fmaf(p.z, wo.z, dd); dd = fmaf(p.w, wo.w, dd);
  }
#pragma unroll
  for (int m = 1; m < 8; m <<= 1) {
    di += __shfl_xor(di, m);
    dg += __shfl_xor(dg, m);
    dd += __shfl_xor(dd, m);
  }
  if (ch == 0 && s < nseg) {
    di += b_ih[j] + b_hh[j];
    dg += b_ih[2 * HDIM + j] + b_hh[2 * HDIM + j];
    dd += b_ih[3 * HDIM + j] + b_hh[3 * HDIM + j];
    float ig = 1.f / (1.f + expf(-di));
    float gg = tanhf(dg);
    float og = 1.f / (1.f + expf(-dd));
    h[(size_t)s * HDIM + j] = og * tanhf(ig * gg);
  }
}

// ---------------------------------------------------------------------------
// L2: ctx[s][col] = b_proj[col] + h[s]·W_proj[col].
// ---------------------------------------------------------------------------
__global__ __launch_bounds__(256) void ctx_kernel(
    const float* __restrict__ h, const float* __restrict__ W_proj,
    const float* __restrict__ b_proj, float* __restrict__ ctx, int nseg) {
  __shared__ float hs[MAXSEG * HDIM];
  int t = threadIdx.x;
  {
    const float4* hsrc = (const float4*)h;
    float4* hdst = (float4*)hs;
#pragma unroll
    for (int i = 0; i < 4; ++i) hdst[i * 256 + t] = hsrc[i * 256 + t];
  }
  __syncthreads();

  int wv = t >> 6, l = t & 63;
  int col = (int)blockIdx.x * 4 + wv;
  int s = l >> 3, ch = l & 7;

  const float4* Wp4 = (const float4*)(W_proj + (size_t)col * HDIM);
  const float4* h4 = (const float4*)(hs + s * HDIM);
  float acc = 0.f;
#pragma unroll
  for (int i = 0; i < 16; ++i) {
    int j4 = ch * 16 + i;
    float4 hv = h4[j4];
    float4 w = Wp4[j4];
    acc = fmaf(hv.x, w.x, acc); acc = fmaf(hv.y, w.y, acc);
    acc = fmaf(hv.z, w.z, acc); acc = fmaf(hv.w, w.w, acc);
  }
#pragma unroll
  for (int m = 1; m < 8; m <<= 1) acc += __shfl_xor(acc, m);
  if (ch == 0 && s < nseg) ctx[s * CDIM + col] = acc + b_proj[col];
}

// ---------------------------------------------------------------------------
// L3: delta[s][k] = ctx[s]·W_head[k]  (b_head already applied in pass A).
// ---------------------------------------------------------------------------
__global__ __launch_bounds__(256) void delta_kernel(
    const float* __restrict__ ctx, const float* __restrict__ W_head,
    float* __restrict__ delta, int nseg) {
  __shared__ float cs[MAXSEG * CDIM];
  int t = threadIdx.x;
  {
    const float4* csrc = (const float4*)ctx;
    float4* cdst = (float4*)cs;
#pragma unroll
    for (int i = 0; i < 2; ++i) cdst[i * 256 + t] = csrc[i * 256 + t];
  }
  __syncthreads();

  int wv = t >> 6, l = t & 63;
  int k = (int)blockIdx.x * 4 + wv;
  if (k >= KCLS) return;
  int s = l >> 3, ch = l & 7;

  const float4* Wh4 = (const float4*)(W_head + (size_t)k * CDIM);
  const float4* c4 = (const float4*)(cs + s * CDIM);
  float acc = 0.f;
#pragma unroll
  for (int i = 0; i < 8; ++i) {
    int idx = ch * 8 + i;
    float4 cv = c4[idx];
    float4 w = Wh4[idx];
    acc = fmaf(cv.x, w.x, acc); acc = fmaf(cv.y, w.y, acc);
    acc = fmaf(cv.z, w.z, acc); acc = fmaf(cv.w, w.w, acc);
  }
#pragma unroll
  for (int m = 1; m < 8; m <<= 1) acc += __shfl_xor(acc, m);
  if (ch == 0 && s < nseg) delta[s * KCLS + k] = acc;
}

// ---------------------------------------------------------------------------
// Pass C: out[r][k] += delta[seg(r)][k], float4 grid-stride.
// ---------------------------------------------------------------------------
__global__ __launch_bounds__(256) void add_delta_kernel(
    float* __restrict__ out, const int* __restrict__ offset,
    const float* __restrict__ delta, int n, int nseg) {
  __shared__ float dl[MAXSEG * KCLS];
  int t = threadIdx.x;
  if (t < MAXSEG * KCLS) dl[t] = (t < nseg * KCLS) ? delta[t] : 0.f;
  __syncthreads();

  int off[MAXSEG];
#pragma unroll
  for (int q = 0; q < MAXSEG; ++q) off[q] = (q < nseg) ? offset[q] : 0x7fffffff;

  long tot = (long)n * (KCLS / 4);
  long stride = (long)gridDim.x * 256;
  for (long e4 = (long)blockIdx.x * 256 + t; e4 < tot; e4 += stride) {
    long row = e4 / 5;
    int k0 = (int)(e4 - row * 5) * 4;
    int s = 0;
#pragma unroll
    for (int q = 0; q < MAXSEG - 1; ++q) s += (row >= off[q]) ? 1 : 0;
    float4 v = ((float4*)out)[e4];
    const float* d = &dl[s * KCLS + k0];
    v.x += d[0]; v.y += d[1]; v.z += d[2]; v.w += d[3];
    ((float4*)out)[e4] = v;
  }
}

extern "C" void kernel_launch(void* const* d_in, const int* in_sizes, int n_in,
                              void* d_out, int out_size, void* d_ws, size_t ws_size,
                              hipStream_t stream) {
  const float* feat   = (const float*)d_in[0];
  const int*   offset = (const int*)d_in[1];
  const float* W_ih   = (const float*)d_in[2];
  const float* b_ih   = (const float*)d_in[3];
  // d_in[4] = W_hh : unused (h0 == 0)
  const float* b_hh   = (const float*)d_in[5];
  const float* W_proj = (const float*)d_in[6];
  const float* b_proj = (const float*)d_in[7];
  const float* W_head = (const float*)d_in[8];
  const float* b_head = (const float*)d_in[9];
  float* out = (float*)d_out;

  int n = in_sizes[0] / CDIM;
  int nseg = in_sizes[1];
  if (nseg > MAXSEG) nseg = MAXSEG;

  float* ws    = (float*)d_ws;
  float* sums  = ws;                                    // 8*256
  float* h     = ws + MAXSEG * CDIM;                    // 8*512
  float* ctx   = ws + MAXSEG * CDIM + MAXSEG * HDIM;    // 8*256
  float* delta = ctx + MAXSEG * CDIM;                   // 8*20

  hipMemsetAsync(sums, 0, MAXSEG * CDIM * sizeof(float), stream);
  fused_pool_head_kernel<<<GRIDA, NTHR, 0, stream>>>(feat, offset, W_head, b_head,
                                                     sums, out, n, nseg);
  lstm_h_kernel<<<128, 256, 0, stream>>>(sums, offset, W_ih, b_ih, b_hh, h, nseg);
  ctx_kernel<<<64, 256, 0, stream>>>(h, W_proj, b_proj, ctx, nseg);
  delta_kernel<<<5, 256, 0, stream>>>(ctx, W_head, delta, nseg);
  add_delta_kernel<<<2560, 256, 0, stream>>>(out, offset, delta, n, nseg);
}